// Round 14
// baseline (201.902 us; speedup 1.0000x reference)
//
#include <hip/hip_runtime.h>
#include <hip/hip_bf16.h>
#include <stdint.h>

#define DEVI __device__ __forceinline__

using u16 = unsigned short;
typedef __attribute__((ext_vector_type(8))) _Float16 halfx8;
typedef __attribute__((ext_vector_type(8))) unsigned short u16x8;
typedef __attribute__((ext_vector_type(4))) float f32x4;

// Problem dims (fixed by the reference)
constexpr int BB = 4, TT = 2048, CC = 1024, KD = 1024, VD = 1024;
constexpr int QKVW = 3072;                 // fused projection width
constexpr int OUTW = CC + VD;              // 2048
constexpr float INV_SQRT_K = 0.03125f;     // 1/sqrt(1024)

DEVI u16 f2h(float f) {
  _Float16 h = (_Float16)f;
  return __builtin_bit_cast(u16, h);
}
DEVI float h2f(u16 u) {
  return (float)__builtin_bit_cast(_Float16, u);
}

// async global->LDS, 16 B per lane. LDS dest is wave-uniform base + lane*16.
DEVI void gload16(const u16* g, u16* l) {
  __builtin_amdgcn_global_load_lds(
      (const __attribute__((address_space(1))) void*)g,
      (__attribute__((address_space(3))) void*)l, 16, 0, 0);
}

// ---- cast x to f16, copy x into out[:, :C], zero out[:, C:] (PV atomics) ----
__global__ void cast_x_copy(const float* __restrict__ x, u16* __restrict__ xh,
                            float* __restrict__ out) {
  size_t i = (size_t)blockIdx.x * blockDim.x + threadIdx.x;  // over B*T*C/4
  float4 v = reinterpret_cast<const float4*>(x)[i];
  ushort4 u;
  u.x = f2h(v.x); u.y = f2h(v.y); u.z = f2h(v.z); u.w = f2h(v.w);
  reinterpret_cast<ushort4*>(xh)[i] = u;
  size_t e = i * 4;
  size_t bt = e / CC;
  int c = (int)(e % CC);
  *reinterpret_cast<float4*>(&out[bt * OUTW + c]) = v;
  float4 z = {0.f, 0.f, 0.f, 0.f};                  // zero the read region:
  *reinterpret_cast<float4*>(&out[bt * OUTW + CC + c]) = z;  // PV accumulates atomically
}

// ---- W{q,k,v} [C,N] f32 -> Wt sections [N,C] f16, one launch (z selects W) ----
__global__ void transpose_cast_w3(const float* __restrict__ Wq,
                                  const float* __restrict__ Wk,
                                  const float* __restrict__ Wv,
                                  u16* __restrict__ Wt) {
  __shared__ float tile[32][33];
  const float* W = (blockIdx.z == 0) ? Wq : (blockIdx.z == 1) ? Wk : Wv;
  u16* dst = Wt + (size_t)blockIdx.z * 1024 * 1024;
  int n0 = blockIdx.x * 32, c0 = blockIdx.y * 32;
  int tx = threadIdx.x, ty = threadIdx.y;  // 32 x 8
  for (int i = ty; i < 32; i += 8)
    tile[i][tx] = W[(size_t)(c0 + i) * KD + n0 + tx];
  __syncthreads();
  for (int i = ty; i < 32; i += 8)
    dst[(size_t)(n0 + i) * CC + c0 + tx] = f2h(tile[tx][i]);
}

// ---- concat biases -> bc[3072] ----
__global__ void concat_bias(const float* __restrict__ bq, const float* __restrict__ bk,
                            const float* __restrict__ bv, float* __restrict__ bc) {
  int n = blockIdx.x * 256 + threadIdx.x;
  float v = (n < 1024) ? bq[n] : (n < 2048) ? bk[n - 1024] : bv[n - 2048];
  bc[n] = v;
}

// ---- V cols of QKV [B*T,3072] -> Vt [B,VD,T] f16, scaled by 1/sum ----
// Folds stats_combine: di = 1 / sum_rt Dp[rt][b][s] (rt >= s>>8; earlier tiles
// were causally skipped and never written).
__global__ void transpose_v(const u16* __restrict__ QKV, const float* __restrict__ Dp,
                            u16* __restrict__ Vt) {
  __shared__ u16 tile[32][33];
  int b = blockIdx.z;
  int n0 = blockIdx.x * 32, s0 = blockIdx.y * 32;
  const u16* src = QKV + (size_t)b * TT * QKVW + 2048;  // V columns
  u16* dst = Vt + (size_t)b * VD * TT;
  int tx = threadIdx.x, ty = threadIdx.y;
  for (int i = ty; i < 32; i += 8)
    tile[i][tx] = src[(size_t)(s0 + i) * QKVW + n0 + tx];
  const int s = s0 + tx;
  float d = 0.f;
  for (int rt = s >> 8; rt < TT / 256; ++rt)
    d += Dp[((size_t)rt * BB + b) * TT + s];
  float di = 1.f / d;  // column contains the diagonal -> d > 0
  __syncthreads();
  for (int i = ty; i < 32; i += 8)
    dst[(size_t)(n0 + i) * TT + s0 + tx] = f2h(h2f(tile[tx][i]) * di);
}

// ---- 256x128-tile 8-wave f16 MFMA GEMM — R12-proven loop (3 buf, depth-2) ----
// Out = alpha*(A @ Bm^T)(+bias). A:[M,Kd] (lda), Bm:[N,Kd] (ldb), row-major.
// 3 LDS buffers, BK=32, 2-deep counted-vmcnt pipeline. 74 KB -> 2 blocks/CU.
// Measured: 62us proj (~830 TF), MfmaUtil 35% — LDS-BW-bound (176 KB/CU/K-tile
// at 128 B/cyc = 1375 cyc vs 512 cyc MFMA -> 37% predicted = matches).
// Race-free: stage(kt+2) targets buf (kt+2)%3 = (kt-1)%3, whose ds_reads all
// completed before barrier(kt-1). vmcnt(3) at kt's end = kt+1's 3 loads landed,
// kt+2's in flight (never drains to 0 in steady state).
// Swizzle (both-sides, rule 21): linear LDS dest; source col-chunk and read
// col-chunk XORed with (row>>1)&3 -> conflict-free b128 (verified R5-R13: 0).
// SWZ==1: row-strip XCD swizzle (uniform-cost grids only; gx%8==0).
// CMASK: S-mode epilogue — P = exp(alpha*acc) for t>=s else 0 (f16; no max
//   subtraction: |alpha*S|<=~4) + fused column-sum partials into Dp.
// PVS: split-K PV mode — blockIdx.x = chunk id (12 per (n,b)), decoded to
//   (rt, kchunk): r0 = rt*256, K-range [c*1024, min((rt+1)*256, c*1024+1024)).
//   Deepest chunks first (balance). Output accumulated via atomicAdd (out
//   region pre-zeroed in cast_x_copy; each element gets <= 2 atomics).
template <typename OutT, int SWZ, bool CSKIP, bool KLIM, bool BIAS, bool CMASK, bool PVS>
__global__ __launch_bounds__(512, 2) void gemm_bt(
    const u16* __restrict__ A, const u16* __restrict__ Bm, OutT* __restrict__ Out,
    const float* __restrict__ bias, float* __restrict__ Dp,
    int Kd, int lda, int ldb, int ldo,
    long long strA, long long strB, long long strO, float alpha) {
  constexpr int BM = 256, BN = 128, BK = 32;
  constexpr int WM = 4, WN = 2;                // wave grid; wave tile 64x64
  constexpr int WR = 64, WC = 64;
  constexpr int MR = 4, NR = 4;                // frags per wave
  constexpr int ASZ = BM * BK, BSZ = BN * BK;  // u16 per buffer
  __shared__ u16 sA[3 * ASZ];  // 48 KB
  __shared__ u16 sB[3 * BSZ];  // 24 KB -> 74 KB total incl. reds -> 2 blocks/CU
  __shared__ float reds[CMASK ? WM : 1][CMASK ? BN : 1];

  int bx = blockIdx.x, by = blockIdx.y;
  int kbeg = 0, kend = Kd;
  if constexpr (PVS) {
    // chunk table, depth-descending: rt {3,4,5,6,7,7,2,6,1,5,0,4}, c {0,0,0,0,0,1,0,1,0,1,0,1}
    const unsigned long long RTP = 0x405162776543ull;  // nibble cid -> rt
    const int rt = (int)((RTP >> (4 * bx)) & 15);
    const int cch = (0xAA0 >> bx) & 1;                 // bits 5,7,9,11
    bx = rt;
    kbeg = cch << 10;
    int ke = (rt + 1) * 256, kcap = kbeg + 1024;
    kend = ke < kcap ? ke : kcap;
  } else if constexpr (SWZ == 1) {
    const int gx = gridDim.x;
    const int nx = gx >> 3;  // bx strip per XCD (gx % 8 == 0 at call sites)
    int fid = bx + gx * by;
    int xcd = fid & 7, idx = fid >> 3;
    bx = xcd * nx + idx % nx;
    by = idx / nx;
  }
  const int r0 = bx * BM, c0 = by * BN;
  if (!PVS && CSKIP && c0 > r0 + BM - 1) return;  // fully masked tile
  A   += (size_t)blockIdx.z * strA + kbeg;
  Bm  += (size_t)blockIdx.z * strB + kbeg;
  Out += (size_t)blockIdx.z * strO;

  const int tid = threadIdx.x;
  const int lane = tid & 63;
  const int w = tid >> 6;            // 0..7
  const int wm = w / WN, wn = w % WN;
  const int l15 = lane & 15, l4 = lane >> 4;
  const int cswz8 = 8 * (l4 ^ ((l15 >> 1) & 3));  // swizzled read col (u16)

  // staging map: thread t covers row t>>2 (0..127; +128 for A line1), chunk t&3.
  // LDS dest linear (byte t*16); global source chunk pre-swizzled (rule 21).
  const int srow = tid >> 2;
  const int sc8 = 8 * ((tid & 3) ^ ((tid >> 3) & 3));  // chunk ^ ((srow>>1)&3)
  const u16* gA  = A  + (size_t)(r0 + srow) * lda + sc8;
  const u16* gA2 = gA + (size_t)128 * lda;
  const u16* gB  = Bm + (size_t)(c0 + srow) * ldb + sc8;
  const int sdst = tid * 8;  // u16 offset; A line1 at +4096

  f32x4 acc[MR][NR] = {};

  int kmax = kend - kbeg;
  if (!PVS && KLIM) { int km = r0 + BM; kmax = km < kmax ? km : kmax; }
  const int NT = kmax / BK;  // >= 8 at all call sites

  auto stage = [&](int buf, int kt) {
    const int k0 = kt * BK;
    u16* da = sA + buf * ASZ + sdst;
    gload16(gA + k0, da);
    gload16(gA2 + k0, da + 4096);
    u16* db = sB + buf * BSZ + sdst;
    gload16(gB + k0, db);
  };

  stage(0, 0);
  stage(1, 1);
  asm volatile("s_waitcnt vmcnt(3)" ::: "memory");  // K-tile 0 landed (in-order)
  __builtin_amdgcn_s_barrier();

  int buf = 0;
  for (int kt = 0; kt < NT; ++kt) {
    int nb = buf + 2; if (nb >= 3) nb -= 3;  // (kt+2)%3
    const u16* rA = sA + buf * ASZ;
    const u16* rB = sB + buf * BSZ;
    halfx8 af[MR], bfv[NR];
#pragma unroll
    for (int n = 0; n < NR; ++n)
      bfv[n] = *reinterpret_cast<const halfx8*>(&rB[(wn * WC + n * 16 + l15) * BK + cswz8]);
#pragma unroll
    for (int m = 0; m < MR; ++m)
      af[m] = *reinterpret_cast<const halfx8*>(&rA[(wm * WR + m * 16 + l15) * BK + cswz8]);
    if (kt + 2 < NT) stage(nb, kt + 2);
    __builtin_amdgcn_s_setprio(1);
#pragma unroll
    for (int m = 0; m < MR; ++m)
#pragma unroll
      for (int n = 0; n < NR; ++n)
        acc[m][n] = __builtin_amdgcn_mfma_f32_16x16x32_f16(af[m], bfv[n], acc[m][n], 0, 0, 0);
    __builtin_amdgcn_s_setprio(0);
    if (kt + 2 < NT)      asm volatile("s_waitcnt vmcnt(3)" ::: "memory");  // kt+1 landed
    else if (kt + 1 < NT) asm volatile("s_waitcnt vmcnt(0)" ::: "memory");  // drain tail
    if (kt + 1 < NT) __builtin_amdgcn_s_barrier();
    buf = buf + 1; if (buf == 3) buf = 0;
  }

  // epilogue: C/D layout col = lane&15, row = (lane>>4)*4 + reg  [m89/m91 verified]
  if constexpr (CMASK) {
    // P = exp(alpha*S) masked to t>=s, f16; fused column-sum partials.
#pragma unroll
    for (int n = 0; n < NR; ++n) {
      const int gcol = c0 + wn * WC + n * 16 + l15;
      float sm = 0.f;
#pragma unroll
      for (int m = 0; m < MR; ++m) {
        const int growb = r0 + wm * WR + m * 16 + l4 * 4;
#pragma unroll
        for (int r = 0; r < 4; ++r) {
          float p = 0.f;
          if (growb + r >= gcol) p = __expf(acc[m][n][r] * alpha);
          reinterpret_cast<u16*>(Out)[(size_t)(growb + r) * ldo + gcol] = f2h(p);
          sm += p;
        }
      }
      sm += __shfl_xor(sm, 16);
      sm += __shfl_xor(sm, 32);  // sum over this wave's 64 rows
      if (l4 == 0) reds[wm][wn * WC + n * 16 + l15] = sm;
    }
    __syncthreads();
    if (tid < BN) {  // combine WM row-strips, write block partial sum
      float d2 = 0.f;
#pragma unroll
      for (int i = 0; i < WM; ++i) d2 += reds[i][tid];
      Dp[((size_t)(r0 >> 8) * BB + blockIdx.z) * TT + c0 + tid] = d2;
    }
  } else {
#pragma unroll
    for (int m = 0; m < MR; ++m) {
      const int growb = r0 + wm * WR + m * 16 + l4 * 4;
#pragma unroll
      for (int n = 0; n < NR; ++n) {
        const int gcol = c0 + wn * WC + n * 16 + l15;
        float bvv = 0.f;
        if (BIAS) bvv = bias[gcol];
#pragma unroll
        for (int r = 0; r < 4; ++r) {
          float val = acc[m][n][r] * alpha + bvv;
          size_t off = (size_t)(growb + r) * ldo + gcol;
          if constexpr (PVS) {
            atomicAdd(&reinterpret_cast<float*>(Out)[off], val);
          } else if constexpr (sizeof(OutT) == 2) {
            reinterpret_cast<u16*>(Out)[off] = f2h(val);
          } else {
            reinterpret_cast<float*>(Out)[off] = val;
          }
        }
      }
    }
  }
}

extern "C" void kernel_launch(void* const* d_in, const int* in_sizes, int n_in,
                              void* d_out, int out_size, void* d_ws, size_t ws_size,
                              hipStream_t stream) {
  const float* x  = (const float*)d_in[0];
  const float* Wq = (const float*)d_in[1];
  const float* bq = (const float*)d_in[2];
  const float* Wk = (const float*)d_in[3];
  const float* bk = (const float*)d_in[4];
  const float* Wv = (const float*)d_in[5];
  const float* bv = (const float*)d_in[6];
  float* out = (float*)d_out;
  char* ws = (char*)d_ws;
  constexpr size_t MB = 1024ull * 1024ull;

  // Workspace layout (max 135 MB), sequential-reuse aliases:
  u16* xh   = (u16*)(ws);              // 16 MB  [B*T, C] f16   (dead after proj)
  u16* QKV  = (u16*)(ws + 16 * MB);    // 48 MB  [B*T, 3072] f16: Q|K|V columns
  u16* Wt   = (u16*)(ws + 64 * MB);    // 6 MB   [3072, C] f16  (dead after proj)
  float* bc = (float*)(ws + 70 * MB);  // 12 KB  concat bias
  u16* SP   = (u16*)(ws + 71 * MB);    // 32 MB  [B,T,T] f16: P = exp(alpha*S)
  u16* Vt = xh;                        // alias: [B,VD,T] f16
  float* Dp = (float*)(ws + 64 * MB);  // alias Wt (dead after proj): 256 KB [8,B,T]

  cast_x_copy<<<dim3((BB * TT * CC / 4) / 256), dim3(256), 0, stream>>>(x, xh, out);
  dim3 tb(32, 8);
  transpose_cast_w3<<<dim3(KD / 32, CC / 32, 3), tb, 0, stream>>>(Wq, Wk, Wv, Wt);
  concat_bias<<<dim3(QKVW / 256), 256, 0, stream>>>(bq, bk, bv, bc);

  // fused projection: QKV = xh @ Wt^T + bc, row-strip XCD swizzle (gx=32)
  gemm_bt<u16, 1, false, false, true, false, false><<<dim3(32, QKVW / 128, 1), 512, 0, stream>>>(
      xh, Wt, QKV, bc, nullptr, CC, CC, CC, QKVW, 0, 0, 0, 1.f);

  // P = exp((Q @ K^T)/sqrt(K)) masked, f16; causal tiles skipped; fused col sums
  gemm_bt<u16, 0, true, false, false, true, false><<<dim3(TT / 256, TT / 128, BB), 512, 0, stream>>>(
      QKV, QKV + 1024, SP, nullptr, Dp, KD, QKVW, QKVW, TT,
      (long long)TT * QKVW, (long long)TT * QKVW, (long long)TT * TT, INV_SQRT_K);

  // Vt = (V cols of QKV)^T scaled by 1/colsum (stats_combine folded in)
  transpose_v<<<dim3(VD / 32, TT / 32, BB), tb, 0, stream>>>(QKV, Dp, Vt);

  // read = P @ (Di*V): split-K PV, 12 depth-sorted chunks x 8 n-tiles x 4
  // batches = 384 balanced blocks; atomicAdd into pre-zeroed out[:, C:].
  gemm_bt<float, 0, false, false, false, false, true><<<dim3(12, VD / 128, BB), 512, 0, stream>>>(
      SP, Vt, out + CC, nullptr, nullptr, TT, TT, TT, OUTW,
      (long long)TT * TT, (long long)VD * TT, (long long)TT * OUTW, 1.f);
}

// Round 15
// 187.198 us; speedup vs baseline: 1.0785x; 1.0785x over previous
//
#include <hip/hip_runtime.h>
#include <hip/hip_bf16.h>
#include <stdint.h>

#define DEVI __device__ __forceinline__

using u16 = unsigned short;
typedef __attribute__((ext_vector_type(8))) _Float16 halfx8;
typedef __attribute__((ext_vector_type(8))) unsigned short u16x8;
typedef __attribute__((ext_vector_type(4))) float f32x4;

// Problem dims (fixed by the reference)
constexpr int BB = 4, TT = 2048, CC = 1024, KD = 1024, VD = 1024;
constexpr int QKVW = 3072;                 // fused projection width
constexpr int OUTW = CC + VD;              // 2048
constexpr float INV_SQRT_K = 0.03125f;     // 1/sqrt(1024)

DEVI u16 f2h(float f) {
  _Float16 h = (_Float16)f;
  return __builtin_bit_cast(u16, h);
}
DEVI float h2f(u16 u) {
  return (float)__builtin_bit_cast(_Float16, u);
}

// async global->LDS, 16 B per lane. LDS dest is wave-uniform base + lane*16.
DEVI void gload16(const u16* g, u16* l) {
  __builtin_amdgcn_global_load_lds(
      (const __attribute__((address_space(1))) void*)g,
      (__attribute__((address_space(3))) void*)l, 16, 0, 0);
}

// ---- cast x to f16 (for MFMA) and copy x into out[:, :C] (fp32) ----
__global__ void cast_x_copy(const float* __restrict__ x, u16* __restrict__ xh,
                            float* __restrict__ out) {
  size_t i = (size_t)blockIdx.x * blockDim.x + threadIdx.x;  // over B*T*C/4
  float4 v = reinterpret_cast<const float4*>(x)[i];
  ushort4 u;
  u.x = f2h(v.x); u.y = f2h(v.y); u.z = f2h(v.z); u.w = f2h(v.w);
  reinterpret_cast<ushort4*>(xh)[i] = u;
  size_t e = i * 4;
  size_t bt = e / CC;
  int c = (int)(e % CC);
  *reinterpret_cast<float4*>(&out[bt * OUTW + c]) = v;
}

// ---- W{q,k,v} [C,N] f32 -> Wt sections [N,C] f16, one launch (z selects W) ----
__global__ void transpose_cast_w3(const float* __restrict__ Wq,
                                  const float* __restrict__ Wk,
                                  const float* __restrict__ Wv,
                                  u16* __restrict__ Wt) {
  __shared__ float tile[32][33];
  const float* W = (blockIdx.z == 0) ? Wq : (blockIdx.z == 1) ? Wk : Wv;
  u16* dst = Wt + (size_t)blockIdx.z * 1024 * 1024;
  int n0 = blockIdx.x * 32, c0 = blockIdx.y * 32;
  int tx = threadIdx.x, ty = threadIdx.y;  // 32 x 8
  for (int i = ty; i < 32; i += 8)
    tile[i][tx] = W[(size_t)(c0 + i) * KD + n0 + tx];
  __syncthreads();
  for (int i = ty; i < 32; i += 8)
    dst[(size_t)(n0 + i) * CC + c0 + tx] = f2h(tile[tx][i]);
}

// ---- concat biases -> bc[3072] ----
__global__ void concat_bias(const float* __restrict__ bq, const float* __restrict__ bk,
                            const float* __restrict__ bv, float* __restrict__ bc) {
  int n = blockIdx.x * 256 + threadIdx.x;
  float v = (n < 1024) ? bq[n] : (n < 2048) ? bk[n - 1024] : bv[n - 2048];
  bc[n] = v;
}

// ---- V cols of QKV [B*T,3072] -> Vt [B,VD,T] f16, scaled by 1/colsum ----
// Folds stats_combine: di = 1 / sum_rt Dp[rt][b][s] (rt >= s>>8; earlier tiles
// were causally skipped and never written).
__global__ void transpose_v(const u16* __restrict__ QKV, const float* __restrict__ Dp,
                            u16* __restrict__ Vt) {
  __shared__ u16 tile[32][33];
  int b = blockIdx.z;
  int n0 = blockIdx.x * 32, s0 = blockIdx.y * 32;
  const u16* src = QKV + (size_t)b * TT * QKVW + 2048;  // V columns
  u16* dst = Vt + (size_t)b * VD * TT;
  int tx = threadIdx.x, ty = threadIdx.y;
  for (int i = ty; i < 32; i += 8)
    tile[i][tx] = src[(size_t)(s0 + i) * QKVW + n0 + tx];
  const int s = s0 + tx;
  float d = 0.f;
  for (int rt = s >> 8; rt < TT / 256; ++rt)
    d += Dp[((size_t)rt * BB + b) * TT + s];
  float di = 1.f / d;  // column contains the diagonal -> d > 0
  __syncthreads();
  for (int i = ty; i < 32; i += 8)
    dst[(size_t)(n0 + i) * TT + s0 + tx] = f2h(h2f(tile[tx][i]) * di);
}

// ---- 256x128-tile 8-wave f16 MFMA GEMM — R12-proven loop (3 buf, depth-2) ----
// Out = alpha*(A @ Bm^T)(+bias). A:[M,Kd] (lda), Bm:[N,Kd] (ldb), row-major.
// 3 LDS buffers, BK=32, 2-deep counted-vmcnt pipeline. 74 KB -> 2 blocks/CU.
// Measured: 62us proj (~830 TF), MfmaUtil 35% — LDS-BW-bound (176 KB/CU/K-tile
// at 128 B/cyc = 1375 cyc vs 512 cyc MFMA -> 37% predicted = matches). Failed
// alternatives (do not retry): 8-phase ports (R6/R13: 74-76us), depth-1/2-buf
// (R11: 72us), 4-buf@1blk (R8), split-K atomics (R14: +16us total).
// Race-free: stage(kt+2) targets buf (kt+2)%3 = (kt-1)%3, whose ds_reads all
// completed before barrier(kt-1). vmcnt(3) at kt's end = kt+1's 3 loads landed,
// kt+2's in flight (never drains to 0 in steady state).
// Swizzle (both-sides, rule 21): linear LDS dest; source col-chunk and read
// col-chunk XORed with (row>>1)&3 -> conflict-free b128 (verified R5-R14: 0).
// SWZ==1: row-strip XCD swizzle (uniform-cost grids only; gx%8==0).
// CMASK: S-mode epilogue — P = exp(alpha*acc) for t>=s else 0 (f16; no max
//   subtraction: |alpha*S|<=~4) + fused column-sum partials into Dp.
// KLIM: PV mode — K truncated at r0+BM (exact: P==0 above diagonal) and
//   deepest-first dispatch (bx -> gx-1-bx: K=2048 tiles start first, shallow
//   tiles backfill -> shorter makespan tail at 1 block/CU).
template <typename OutT, int SWZ, bool CSKIP, bool KLIM, bool BIAS, bool CMASK>
__global__ __launch_bounds__(512, 2) void gemm_bt(
    const u16* __restrict__ A, const u16* __restrict__ Bm, OutT* __restrict__ Out,
    const float* __restrict__ bias, float* __restrict__ Dp,
    int Kd, int lda, int ldb, int ldo,
    long long strA, long long strB, long long strO, float alpha) {
  constexpr int BM = 256, BN = 128, BK = 32;
  constexpr int WM = 4, WN = 2;                // wave grid; wave tile 64x64
  constexpr int WR = 64, WC = 64;
  constexpr int MR = 4, NR = 4;                // frags per wave
  constexpr int ASZ = BM * BK, BSZ = BN * BK;  // u16 per buffer
  __shared__ u16 sA[3 * ASZ];  // 48 KB
  __shared__ u16 sB[3 * BSZ];  // 24 KB -> 74 KB total incl. reds -> 2 blocks/CU
  __shared__ float reds[CMASK ? WM : 1][CMASK ? BN : 1];

  int bx = blockIdx.x, by = blockIdx.y;
  if constexpr (KLIM) {
    bx = gridDim.x - 1 - bx;  // deepest-first dispatch order
  } else if constexpr (SWZ == 1) {
    const int gx = gridDim.x;
    const int nx = gx >> 3;  // bx strip per XCD (gx % 8 == 0 at call sites)
    int fid = bx + gx * by;
    int xcd = fid & 7, idx = fid >> 3;
    bx = xcd * nx + idx % nx;
    by = idx / nx;
  }
  const int r0 = bx * BM, c0 = by * BN;
  if (CSKIP && c0 > r0 + BM - 1) return;  // tile fully masked; never read downstream
  A   += (size_t)blockIdx.z * strA;
  Bm  += (size_t)blockIdx.z * strB;
  Out += (size_t)blockIdx.z * strO;

  const int tid = threadIdx.x;
  const int lane = tid & 63;
  const int w = tid >> 6;            // 0..7
  const int wm = w / WN, wn = w % WN;
  const int l15 = lane & 15, l4 = lane >> 4;
  const int cswz8 = 8 * (l4 ^ ((l15 >> 1) & 3));  // swizzled read col (u16)

  // staging map: thread t covers row t>>2 (0..127; +128 for A line1), chunk t&3.
  // LDS dest linear (byte t*16); global source chunk pre-swizzled (rule 21).
  const int srow = tid >> 2;
  const int sc8 = 8 * ((tid & 3) ^ ((tid >> 3) & 3));  // chunk ^ ((srow>>1)&3)
  const u16* gA  = A  + (size_t)(r0 + srow) * lda + sc8;
  const u16* gA2 = gA + (size_t)128 * lda;
  const u16* gB  = Bm + (size_t)(c0 + srow) * ldb + sc8;
  const int sdst = tid * 8;  // u16 offset; A line1 at +4096

  f32x4 acc[MR][NR] = {};

  int kmax = Kd;
  if (KLIM) { int km = r0 + BM; kmax = km < Kd ? km : Kd; }
  const int NT = kmax / BK;  // >= 8 at all call sites

  auto stage = [&](int buf, int kt) {
    const int k0 = kt * BK;
    u16* da = sA + buf * ASZ + sdst;
    gload16(gA + k0, da);
    gload16(gA2 + k0, da + 4096);
    u16* db = sB + buf * BSZ + sdst;
    gload16(gB + k0, db);
  };

  stage(0, 0);
  stage(1, 1);
  asm volatile("s_waitcnt vmcnt(3)" ::: "memory");  // K-tile 0 landed (in-order)
  __builtin_amdgcn_s_barrier();

  int buf = 0;
  for (int kt = 0; kt < NT; ++kt) {
    int nb = buf + 2; if (nb >= 3) nb -= 3;  // (kt+2)%3
    const u16* rA = sA + buf * ASZ;
    const u16* rB = sB + buf * BSZ;
    halfx8 af[MR], bfv[NR];
#pragma unroll
    for (int n = 0; n < NR; ++n)
      bfv[n] = *reinterpret_cast<const halfx8*>(&rB[(wn * WC + n * 16 + l15) * BK + cswz8]);
#pragma unroll
    for (int m = 0; m < MR; ++m)
      af[m] = *reinterpret_cast<const halfx8*>(&rA[(wm * WR + m * 16 + l15) * BK + cswz8]);
    if (kt + 2 < NT) stage(nb, kt + 2);
    __builtin_amdgcn_s_setprio(1);
#pragma unroll
    for (int m = 0; m < MR; ++m)
#pragma unroll
      for (int n = 0; n < NR; ++n)
        acc[m][n] = __builtin_amdgcn_mfma_f32_16x16x32_f16(af[m], bfv[n], acc[m][n], 0, 0, 0);
    __builtin_amdgcn_s_setprio(0);
    if (kt + 2 < NT)      asm volatile("s_waitcnt vmcnt(3)" ::: "memory");  // kt+1 landed
    else if (kt + 1 < NT) asm volatile("s_waitcnt vmcnt(0)" ::: "memory");  // drain tail
    if (kt + 1 < NT) __builtin_amdgcn_s_barrier();
    buf = buf + 1; if (buf == 3) buf = 0;
  }

  // epilogue: C/D layout col = lane&15, row = (lane>>4)*4 + reg  [m89/m91 verified]
  if constexpr (CMASK) {
    // P = exp(alpha*S) masked to t>=s, f16; fused column-sum partials.
#pragma unroll
    for (int n = 0; n < NR; ++n) {
      const int gcol = c0 + wn * WC + n * 16 + l15;
      float sm = 0.f;
#pragma unroll
      for (int m = 0; m < MR; ++m) {
        const int growb = r0 + wm * WR + m * 16 + l4 * 4;
#pragma unroll
        for (int r = 0; r < 4; ++r) {
          float p = 0.f;
          if (growb + r >= gcol) p = __expf(acc[m][n][r] * alpha);
          reinterpret_cast<u16*>(Out)[(size_t)(growb + r) * ldo + gcol] = f2h(p);
          sm += p;
        }
      }
      sm += __shfl_xor(sm, 16);
      sm += __shfl_xor(sm, 32);  // sum over this wave's 64 rows
      if (l4 == 0) reds[wm][wn * WC + n * 16 + l15] = sm;
    }
    __syncthreads();
    if (tid < BN) {  // combine WM row-strips, write block partial sum
      float d2 = 0.f;
#pragma unroll
      for (int i = 0; i < WM; ++i) d2 += reds[i][tid];
      Dp[((size_t)(r0 >> 8) * BB + blockIdx.z) * TT + c0 + tid] = d2;
    }
  } else {
#pragma unroll
    for (int m = 0; m < MR; ++m) {
      const int growb = r0 + wm * WR + m * 16 + l4 * 4;
#pragma unroll
      for (int n = 0; n < NR; ++n) {
        const int gcol = c0 + wn * WC + n * 16 + l15;
        float bvv = 0.f;
        if (BIAS) bvv = bias[gcol];
#pragma unroll
        for (int r = 0; r < 4; ++r) {
          float val = acc[m][n][r] * alpha + bvv;
          size_t off = (size_t)(growb + r) * ldo + gcol;
          if constexpr (sizeof(OutT) == 2) {
            reinterpret_cast<u16*>(Out)[off] = f2h(val);
          } else {
            reinterpret_cast<float*>(Out)[off] = val;
          }
        }
      }
    }
  }
}

extern "C" void kernel_launch(void* const* d_in, const int* in_sizes, int n_in,
                              void* d_out, int out_size, void* d_ws, size_t ws_size,
                              hipStream_t stream) {
  const float* x  = (const float*)d_in[0];
  const float* Wq = (const float*)d_in[1];
  const float* bq = (const float*)d_in[2];
  const float* Wk = (const float*)d_in[3];
  const float* bk = (const float*)d_in[4];
  const float* Wv = (const float*)d_in[5];
  const float* bv = (const float*)d_in[6];
  float* out = (float*)d_out;
  char* ws = (char*)d_ws;
  constexpr size_t MB = 1024ull * 1024ull;

  // Workspace layout (max 135 MB), sequential-reuse aliases:
  u16* xh   = (u16*)(ws);              // 16 MB  [B*T, C] f16   (dead after proj)
  u16* QKV  = (u16*)(ws + 16 * MB);    // 48 MB  [B*T, 3072] f16: Q|K|V columns
  u16* Wt   = (u16*)(ws + 64 * MB);    // 6 MB   [3072, C] f16  (dead after proj)
  float* bc = (float*)(ws + 70 * MB);  // 12 KB  concat bias
  u16* SP   = (u16*)(ws + 71 * MB);    // 32 MB  [B,T,T] f16: P = exp(alpha*S)
  u16* Vt = xh;                        // alias: [B,VD,T] f16
  float* Dp = (float*)(ws + 64 * MB);  // alias Wt (dead after proj): 256 KB [8,B,T]

  cast_x_copy<<<dim3((BB * TT * CC / 4) / 256), dim3(256), 0, stream>>>(x, xh, out);
  dim3 tb(32, 8);
  transpose_cast_w3<<<dim3(KD / 32, CC / 32, 3), tb, 0, stream>>>(Wq, Wk, Wv, Wt);
  concat_bias<<<dim3(QKVW / 256), 256, 0, stream>>>(bq, bk, bv, bc);

  // fused projection: QKV = xh @ Wt^T + bc, row-strip XCD swizzle (gx=32)
  gemm_bt<u16, 1, false, false, true, false><<<dim3(32, QKVW / 128, 1), 512, 0, stream>>>(
      xh, Wt, QKV, bc, nullptr, CC, CC, CC, QKVW, 0, 0, 0, 1.f);

  // P = exp((Q @ K^T)/sqrt(K)) masked, f16; causal tiles skipped; fused col sums
  gemm_bt<u16, 0, true, false, false, true><<<dim3(TT / 256, TT / 128, BB), 512, 0, stream>>>(
      QKV, QKV + 1024, SP, nullptr, Dp, KD, QKVW, QKVW, TT,
      (long long)TT * QKVW, (long long)TT * QKVW, (long long)TT * TT, INV_SQRT_K);

  // Vt = (V cols of QKV)^T scaled by 1/colsum (stats_combine folded in)
  transpose_v<<<dim3(VD / 32, TT / 32, BB), tb, 0, stream>>>(QKV, Dp, Vt);

  // read = P @ (Di*V), K truncated at r0+256, deepest tiles dispatched first
  gemm_bt<float, 0, false, true, false, false><<<dim3(TT / 256, VD / 128, BB), 512, 0, stream>>>(
      SP, Vt, out + CC, nullptr, nullptr, TT, TT, TT, OUTW,
      (long long)TT * TT, (long long)VD * TT, (long long)TT * OUTW, 1.f);
}

// Round 16
// 183.876 us; speedup vs baseline: 1.0980x; 1.0181x over previous
//
#include <hip/hip_runtime.h>
#include <hip/hip_bf16.h>
#include <stdint.h>

#define DEVI __device__ __forceinline__

using u16 = unsigned short;
typedef __attribute__((ext_vector_type(8))) _Float16 halfx8;
typedef __attribute__((ext_vector_type(8))) unsigned short u16x8;
typedef __attribute__((ext_vector_type(4))) float f32x4;

constexpr int BB = 4, TT = 2048, CC = 1024, KD = 1024, VD = 1024;
constexpr int QKVW = 3072;
constexpr int OUTW = CC + VD;
constexpr float INV_SQRT_K = 0.03125f;

DEVI u16 f2h(float f) {
  _Float16 h = (_Float16)f;
  return __builtin_bit_cast(u16, h);
}
DEVI float h2f(u16 u) {
  return (float)__builtin_bit_cast(_Float16, u);
}

DEVI void gload16(const u16* g, u16* l) {
  __builtin_amdgcn_global_load_lds(
      (const __attribute__((address_space(1))) void*)g,
      (__attribute__((address_space(3))) void*)l, 16, 0, 0);
}

// ---- cast x to f16 (for MFMA) and copy x into out[:, :C] (fp32) ----
__global__ void cast_x_copy(const float* __restrict__ x, u16* __restrict__ xh,
                            float* __restrict__ out) {
  size_t i = (size_t)blockIdx.x * blockDim.x + threadIdx.x;
  float4 v = reinterpret_cast<const float4*>(x)[i];
  ushort4 u;
  u.x = f2h(v.x); u.y = f2h(v.y); u.z = f2h(v.z); u.w = f2h(v.w);
  reinterpret_cast<ushort4*>(xh)[i] = u;
  size_t e = i * 4;
  size_t bt = e / CC;
  int c = (int)(e % CC);
  *reinterpret_cast<float4*>(&out[bt * OUTW + c]) = v;
}

// ---- W{q,k,v} [C,N] f32 -> Wt sections [N,C] f16 ----
__global__ void transpose_cast_w3(const float* __restrict__ Wq,
                                  const float* __restrict__ Wk,
                                  const float* __restrict__ Wv,
                                  u16* __restrict__ Wt) {
  __shared__ float tile[32][33];
  const float* W = (blockIdx.z == 0) ? Wq : (blockIdx.z == 1) ? Wk : Wv;
  u16* dst = Wt + (size_t)blockIdx.z * 1024 * 1024;
  int n0 = blockIdx.x * 32, c0 = blockIdx.y * 32;
  int tx = threadIdx.x, ty = threadIdx.y;
  for (int i = ty; i < 32; i += 8)
    tile[i][tx] = W[(size_t)(c0 + i) * KD + n0 + tx];
  __syncthreads();
  for (int i = ty; i < 32; i += 8)
    dst[(size_t)(n0 + i) * CC + c0 + tx] = f2h(tile[tx][i]);
}

__global__ void concat_bias(const float* __restrict__ bq, const float* __restrict__ bk,
                            const float* __restrict__ bv, float* __restrict__ bc) {
  int n = blockIdx.x * 256 + threadIdx.x;
  float v = (n < 1024) ? bq[n] : (n < 2048) ? bk[n - 1024] : bv[n - 2048];
  bc[n] = v;
}

// ---- V cols of QKV -> Vt [B,VD,T] f16, scaled by 1/colsum (stats folded) ----
__global__ void transpose_v(const u16* __restrict__ QKV, const float* __restrict__ Dp,
                            u16* __restrict__ Vt) {
  __shared__ u16 tile[32][33];
  int b = blockIdx.z;
  int n0 = blockIdx.x * 32, s0 = blockIdx.y * 32;
  const u16* src = QKV + (size_t)b * TT * QKVW + 2048;
  u16* dst = Vt + (size_t)b * VD * TT;
  int tx = threadIdx.x, ty = threadIdx.y;
  for (int i = ty; i < 32; i += 8)
    tile[i][tx] = src[(size_t)(s0 + i) * QKVW + n0 + tx];
  const int s = s0 + tx;
  float d = 0.f;
  for (int rt = s >> 8; rt < TT / 256; ++rt)
    d += Dp[((size_t)rt * BB + b) * TT + s];
  float di = 1.f / d;
  __syncthreads();
  for (int i = ty; i < 32; i += 8)
    dst[(size_t)(n0 + i) * TT + s0 + tx] = f2h(h2f(tile[tx][i]) * di);
}

// ======== 256x256 8-phase GEMM (progressive half-tile schedule) ========
// Out = alpha*(A@Bm^T)+bias. 8 waves (2M x 4N), wave tile 128x64 (43.7
// FLOP/LDS-byte vs 32 for 64x64 — attacks the measured ~85 B/cyc LDS-read
// bound). BK=64. LDS 128 KB: A[2dbuf][2half][128][64], B same; 1 block/CU.
// INTERLEAVED frag mapping so each phase touches ONE half-tile:
//   A-frag m -> half m>>2, row-in-half wm*64+(m&3)*16+l15
//   B-frag n -> half n>>1, row-in-half wn*32+(n&1)*16+l15
// Phases per K-tile t (db=t&1; stage into db^1 for t+1; 2 loads/half/thread):
//   ph0: vmcnt(4);bar; read af(m0-3,A[db][0],8) + bf01(B[db][0],4);
//        stage Ah0(t+1); 16 MFMA acc[m0-3][n0-1]
//   ph1: vmcnt(4|2);bar; read bf23(B[db][1],4); stage Bh0(t+1);
//        16 MFMA acc[m0-3][n2-3]
//   ph2: vmcnt(4|0);bar; read af(m4-7,A[db][1],8); stage Bh1(t+1);
//        16 MFMA acc[m4-7][n2-3]
//   ph3: (no bar) stage Ah1(t+1); 16 MFMA acc[m4-7][n0-1] (bf01 held in regs)
// LEDGER (loads, in-order): during t-1, t's halves staged in order
// Ah0,Bh0,Bh1,Ah1 (8 loads). ph0's vmcnt(4) -> oldest 4 (Ah0,Bh0) landed;
// ph1's vmcnt(4) (outstanding Bh1,Ah1,Ah0'=6) -> Bh1 landed; ph2's vmcnt(4)
// (outstanding Ah1,Ah0',Bh0'=... <=8) -> Ah1 landed. Tail (t=NT-1, no
// stages): ph1 vmcnt(2), ph2 vmcnt(0). vmcnt is per-wave: each wave stages
// 1/8 of each half with its OWN loads; the barrier AFTER vmcnt makes the
// guarantee collective. Overwrite-race: stage(t+1) targets slots[db^1] last
// READ at t-1, >=2 barriers earlier. Swizzle: LDS[row][c] holds global chunk
// c^(row&7) (src pre-swizzle = read swizzle, rule 21) -> 2-way max on b128.
template <typename OutT, int SWZ, bool BIAS>
__global__ __launch_bounds__(512, 1) void gemm8h(
    const u16* __restrict__ A, const u16* __restrict__ Bm, OutT* __restrict__ Out,
    const float* __restrict__ bias, int Kd, int lda, int ldb, int ldo, float alpha) {
  __shared__ u16 sA[4][8192];  // [db*2+half][128*64] 64 KB
  __shared__ u16 sB[4][8192];  // 64 KB -> 128 KB total

  int bx = blockIdx.x, by = blockIdx.y;
  if constexpr (SWZ == 1) {
    const int gx = gridDim.x;
    const int nx = gx >> 3;
    int fid = bx + gx * by;
    int xcd = fid & 7, idx = fid >> 3;
    bx = xcd * nx + idx % nx;
    by = idx / nx;
  }
  const int r0 = bx * 256, c0 = by * 256;

  const int tid = threadIdx.x;
  const int lane = tid & 63;
  const int w = tid >> 6;
  const int wm = w >> 2, wn = w & 3;  // 2M x 4N
  const int l15 = lane & 15, l4 = lane >> 4;

  // staging map: thread t covers row t>>3 (0..63; +64 sweep1), chunk t&7.
  // source chunk pre-swizzled: c_src = (t&7) ^ (row&7); ((row+64)&7)==row&7.
  const int sr = tid >> 3;
  const int scw = 8 * ((tid & 7) ^ (sr & 7));
  const u16* gA = A + (size_t)(r0 + sr) * lda + scw;
  const u16* gB = Bm + (size_t)(c0 + sr) * ldb + scw;
  const int sdst = tid * 8;  // row*64 + chunk*8 (linear); sweep1 at +4096

  auto stageA = [&](int db, int h, int kt) {
    const u16* p = gA + (size_t)h * 128 * lda + kt * 64;
    u16* d = sA[db * 2 + h] + sdst;
    gload16(p, d);
    gload16(p + (size_t)64 * lda, d + 4096);
  };
  auto stageB = [&](int db, int h, int kt) {
    const u16* p = gB + (size_t)h * 128 * ldb + kt * 64;
    u16* d = sB[db * 2 + h] + sdst;
    gload16(p, d);
    gload16(p + (size_t)64 * ldb, d + 4096);
  };
  // frag reads: row-in-half, chunk (ks*4+l4)^(row&7); row&7 == l15&7
  auto rdA = [&](int db, int h, int mm, int ks) {
    const int row = wm * 64 + mm * 16 + l15;
    return *reinterpret_cast<const halfx8*>(
        &sA[db * 2 + h][row * 64 + (((ks * 4 + l4) ^ (l15 & 7)) * 8)]);
  };
  auto rdB = [&](int db, int h, int nn, int ks) {
    const int row = wn * 32 + nn * 16 + l15;
    return *reinterpret_cast<const halfx8*>(
        &sB[db * 2 + h][row * 64 + (((ks * 4 + l4) ^ (l15 & 7)) * 8)]);
  };

  f32x4 acc[8][4] = {};
  const int NT = Kd / 64;  // >= 2

  // prologue: K-tile 0's halves, in ledger order (8 loads)
  stageA(0, 0, 0);
  stageB(0, 0, 0);
  stageB(0, 1, 0);
  stageA(0, 1, 0);

  halfx8 af[4][2], bf01[2][2], bf23[2][2];
  for (int t = 0; t < NT; ++t) {
    const int db = t & 1, sdb = db ^ 1;
    const bool pre = (t + 1 < NT);
    // ---- ph0 ----
    asm volatile("s_waitcnt vmcnt(4)" ::: "memory");
    __builtin_amdgcn_s_barrier();
#pragma unroll
    for (int mm = 0; mm < 4; ++mm) {
      af[mm][0] = rdA(db, 0, mm, 0);
      af[mm][1] = rdA(db, 0, mm, 1);
    }
#pragma unroll
    for (int nn = 0; nn < 2; ++nn) {
      bf01[nn][0] = rdB(db, 0, nn, 0);
      bf01[nn][1] = rdB(db, 0, nn, 1);
    }
    if (pre) stageA(sdb, 0, t + 1);
    __builtin_amdgcn_s_setprio(1);
#pragma unroll
    for (int mm = 0; mm < 4; ++mm)
#pragma unroll
      for (int nn = 0; nn < 2; ++nn)
#pragma unroll
        for (int ks = 0; ks < 2; ++ks)
          acc[mm][nn] = __builtin_amdgcn_mfma_f32_16x16x32_f16(af[mm][ks], bf01[nn][ks], acc[mm][nn], 0, 0, 0);
    __builtin_amdgcn_s_setprio(0);
    // ---- ph1 ----
    if (pre) asm volatile("s_waitcnt vmcnt(4)" ::: "memory");
    else     asm volatile("s_waitcnt vmcnt(2)" ::: "memory");
    __builtin_amdgcn_s_barrier();
#pragma unroll
    for (int nn = 0; nn < 2; ++nn) {
      bf23[nn][0] = rdB(db, 1, nn, 0);
      bf23[nn][1] = rdB(db, 1, nn, 1);
    }
    if (pre) stageB(sdb, 0, t + 1);
    __builtin_amdgcn_s_setprio(1);
#pragma unroll
    for (int mm = 0; mm < 4; ++mm)
#pragma unroll
      for (int nn = 0; nn < 2; ++nn)
#pragma unroll
        for (int ks = 0; ks < 2; ++ks)
          acc[mm][2 + nn] = __builtin_amdgcn_mfma_f32_16x16x32_f16(af[mm][ks], bf23[nn][ks], acc[mm][2 + nn], 0, 0, 0);
    __builtin_amdgcn_s_setprio(0);
    // ---- ph2 ----
    if (pre) asm volatile("s_waitcnt vmcnt(4)" ::: "memory");
    else     asm volatile("s_waitcnt vmcnt(0)" ::: "memory");
    __builtin_amdgcn_s_barrier();
#pragma unroll
    for (int mm = 0; mm < 4; ++mm) {
      af[mm][0] = rdA(db, 1, mm, 0);
      af[mm][1] = rdA(db, 1, mm, 1);
    }
    if (pre) stageB(sdb, 1, t + 1);
    __builtin_amdgcn_s_setprio(1);
#pragma unroll
    for (int mm = 0; mm < 4; ++mm)
#pragma unroll
      for (int nn = 0; nn < 2; ++nn)
#pragma unroll
        for (int ks = 0; ks < 2; ++ks)
          acc[4 + mm][2 + nn] = __builtin_amdgcn_mfma_f32_16x16x32_f16(af[mm][ks], bf23[nn][ks], acc[4 + mm][2 + nn], 0, 0, 0);
    __builtin_amdgcn_s_setprio(0);
    // ---- ph3 (no barrier: no new LDS reads; bf01 held in registers) ----
    if (pre) stageA(sdb, 1, t + 1);
    __builtin_amdgcn_s_setprio(1);
#pragma unroll
    for (int mm = 0; mm < 4; ++mm)
#pragma unroll
      for (int nn = 0; nn < 2; ++nn)
#pragma unroll
        for (int ks = 0; ks < 2; ++ks)
          acc[4 + mm][nn] = __builtin_amdgcn_mfma_f32_16x16x32_f16(af[mm][ks], bf01[nn][ks], acc[4 + mm][nn], 0, 0, 0);
    __builtin_amdgcn_s_setprio(0);
  }

  // epilogue — interleaved mapping: row = (m>>2)*128 + wm*64 + (m&3)*16 +
  // l4*4 + r; col = (n>>1)*128 + wn*32 + (n&1)*16 + l15. (C/D: col=lane&15,
  // row=(lane>>4)*4+reg, m89/m91.)
#pragma unroll
  for (int m = 0; m < 8; ++m) {
    const int growb = r0 + (m >> 2) * 128 + wm * 64 + (m & 3) * 16 + l4 * 4;
#pragma unroll
    for (int n = 0; n < 4; ++n) {
      const int gcol = c0 + (n >> 1) * 128 + wn * 32 + (n & 1) * 16 + l15;
      float bvv = 0.f;
      if (BIAS) bvv = bias[gcol];
#pragma unroll
      for (int r = 0; r < 4; ++r) {
        float val = acc[m][n][r] * alpha + bvv;
        size_t off = (size_t)(growb + r) * ldo + gcol;
        if constexpr (sizeof(OutT) == 2) {
          reinterpret_cast<u16*>(Out)[off] = f2h(val);
        } else {
          reinterpret_cast<float*>(Out)[off] = val;
        }
      }
    }
  }
}

// ---- R12-proven 256x128 2-phase GEMM (S: CMASK; PV: KLIM) ----
template <typename OutT, int SWZ, bool CSKIP, bool KLIM, bool BIAS, bool CMASK>
__global__ __launch_bounds__(512, 2) void gemm_bt(
    const u16* __restrict__ A, const u16* __restrict__ Bm, OutT* __restrict__ Out,
    const float* __restrict__ bias, float* __restrict__ Dp,
    int Kd, int lda, int ldb, int ldo,
    long long strA, long long strB, long long strO, float alpha) {
  constexpr int BM = 256, BN = 128, BK = 32;
  constexpr int WM = 4, WN = 2;
  constexpr int WR = 64, WC = 64;
  constexpr int MR = 4, NR = 4;
  constexpr int ASZ = BM * BK, BSZ = BN * BK;
  __shared__ u16 sA[3 * ASZ];
  __shared__ u16 sB[3 * BSZ];
  __shared__ float reds[CMASK ? WM : 1][CMASK ? BN : 1];

  int bx = blockIdx.x, by = blockIdx.y;
  if constexpr (KLIM) {
    bx = gridDim.x - 1 - bx;  // deepest-first
  } else if constexpr (SWZ == 1) {
    const int gx = gridDim.x;
    const int nx = gx >> 3;
    int fid = bx + gx * by;
    int xcd = fid & 7, idx = fid >> 3;
    bx = xcd * nx + idx % nx;
    by = idx / nx;
  }
  const int r0 = bx * BM, c0 = by * BN;
  if (CSKIP && c0 > r0 + BM - 1) return;
  A   += (size_t)blockIdx.z * strA;
  Bm  += (size_t)blockIdx.z * strB;
  Out += (size_t)blockIdx.z * strO;

  const int tid = threadIdx.x;
  const int lane = tid & 63;
  const int w = tid >> 6;
  const int wm = w / WN, wn = w % WN;
  const int l15 = lane & 15, l4 = lane >> 4;
  const int cswz8 = 8 * (l4 ^ ((l15 >> 1) & 3));

  const int srow = tid >> 2;
  const int sc8 = 8 * ((tid & 3) ^ ((tid >> 3) & 3));
  const u16* gA  = A  + (size_t)(r0 + srow) * lda + sc8;
  const u16* gA2 = gA + (size_t)128 * lda;
  const u16* gB  = Bm + (size_t)(c0 + srow) * ldb + sc8;
  const int sdst = tid * 8;

  f32x4 acc[MR][NR] = {};

  int kmax = Kd;
  if (KLIM) { int km = r0 + BM; kmax = km < Kd ? km : Kd; }
  const int NT = kmax / BK;

  auto stage = [&](int buf, int kt) {
    const int k0 = kt * BK;
    u16* da = sA + buf * ASZ + sdst;
    gload16(gA + k0, da);
    gload16(gA2 + k0, da + 4096);
    u16* db = sB + buf * BSZ + sdst;
    gload16(gB + k0, db);
  };

  stage(0, 0);
  stage(1, 1);
  asm volatile("s_waitcnt vmcnt(3)" ::: "memory");
  __builtin_amdgcn_s_barrier();

  int buf = 0;
  for (int kt = 0; kt < NT; ++kt) {
    int nb = buf + 2; if (nb >= 3) nb -= 3;
    const u16* rA = sA + buf * ASZ;
    const u16* rB = sB + buf * BSZ;
    halfx8 af[MR], bfv[NR];
#pragma unroll
    for (int n = 0; n < NR; ++n)
      bfv[n] = *reinterpret_cast<const halfx8*>(&rB[(wn * WC + n * 16 + l15) * BK + cswz8]);
#pragma unroll
    for (int m = 0; m < MR; ++m)
      af[m] = *reinterpret_cast<const halfx8*>(&rA[(wm * WR + m * 16 + l15) * BK + cswz8]);
    if (kt + 2 < NT) stage(nb, kt + 2);
    __builtin_amdgcn_s_setprio(1);
#pragma unroll
    for (int m = 0; m < MR; ++m)
#pragma unroll
      for (int n = 0; n < NR; ++n)
        acc[m][n] = __builtin_amdgcn_mfma_f32_16x16x32_f16(af[m], bfv[n], acc[m][n], 0, 0, 0);
    __builtin_amdgcn_s_setprio(0);
    if (kt + 2 < NT)      asm volatile("s_waitcnt vmcnt(3)" ::: "memory");
    else if (kt + 1 < NT) asm volatile("s_waitcnt vmcnt(0)" ::: "memory");
    if (kt + 1 < NT) __builtin_amdgcn_s_barrier();
    buf = buf + 1; if (buf == 3) buf = 0;
  }

  if constexpr (CMASK) {
#pragma unroll
    for (int n = 0; n < NR; ++n) {
      const int gcol = c0 + wn * WC + n * 16 + l15;
      float sm = 0.f;
#pragma unroll
      for (int m = 0; m < MR; ++m) {
        const int growb = r0 + wm * WR + m * 16 + l4 * 4;
#pragma unroll
        for (int r = 0; r < 4; ++r) {
          float p = 0.f;
          if (growb + r >= gcol) p = __expf(acc[m][n][r] * alpha);
          reinterpret_cast<u16*>(Out)[(size_t)(growb + r) * ldo + gcol] = f2h(p);
          sm += p;
        }
      }
      sm += __shfl_xor(sm, 16);
      sm += __shfl_xor(sm, 32);
      if (l4 == 0) reds[wm][wn * WC + n * 16 + l15] = sm;
    }
    __syncthreads();
    if (tid < BN) {
      float d2 = 0.f;
#pragma unroll
      for (int i = 0; i < WM; ++i) d2 += reds[i][tid];
      Dp[((size_t)(r0 >> 8) * BB + blockIdx.z) * TT + c0 + tid] = d2;
    }
  } else {
#pragma unroll
    for (int m = 0; m < MR; ++m) {
      const int growb = r0 + wm * WR + m * 16 + l4 * 4;
#pragma unroll
      for (int n = 0; n < NR; ++n) {
        const int gcol = c0 + wn * WC + n * 16 + l15;
        float bvv = 0.f;
        if (BIAS) bvv = bias[gcol];
#pragma unroll
        for (int r = 0; r < 4; ++r) {
          float val = acc[m][n][r] * alpha + bvv;
          size_t off = (size_t)(growb + r) * ldo + gcol;
          if constexpr (sizeof(OutT) == 2) {
            reinterpret_cast<u16*>(Out)[off] = f2h(val);
          } else {
            reinterpret_cast<float*>(Out)[off] = val;
          }
        }
      }
    }
  }
}

extern "C" void kernel_launch(void* const* d_in, const int* in_sizes, int n_in,
                              void* d_out, int out_size, void* d_ws, size_t ws_size,
                              hipStream_t stream) {
  const float* x  = (const float*)d_in[0];
  const float* Wq = (const float*)d_in[1];
  const float* bq = (const float*)d_in[2];
  const float* Wk = (const float*)d_in[3];
  const float* bk = (const float*)d_in[4];
  const float* Wv = (const float*)d_in[5];
  const float* bv = (const float*)d_in[6];
  float* out = (float*)d_out;
  char* ws = (char*)d_ws;
  constexpr size_t MB = 1024ull * 1024ull;

  u16* xh   = (u16*)(ws);              // 16 MB
  u16* QKV  = (u16*)(ws + 16 * MB);    // 48 MB
  u16* Wt   = (u16*)(ws + 64 * MB);    // 6 MB (dead after proj)
  float* bc = (float*)(ws + 70 * MB);  // 12 KB
  u16* SP   = (u16*)(ws + 71 * MB);    // 32 MB f16 P
  u16* Vt = xh;                        // alias
  float* Dp = (float*)(ws + 64 * MB);  // alias Wt: 256 KB [8,B,T]

  cast_x_copy<<<dim3((BB * TT * CC / 4) / 256), dim3(256), 0, stream>>>(x, xh, out);
  dim3 tb(32, 8);
  transpose_cast_w3<<<dim3(KD / 32, CC / 32, 3), tb, 0, stream>>>(Wq, Wk, Wv, Wt);
  concat_bias<<<dim3(QKVW / 256), 256, 0, stream>>>(bq, bk, bv, bc);

  // fused projection: 8-phase 256x256 kernel, XCD row-strip swizzle (gx=32)
  gemm8h<u16, 1, true><<<dim3(32, QKVW / 256, 1), 512, 0, stream>>>(
      xh, Wt, QKV, bc, CC, CC, CC, QKVW, 1.f);

  // P = exp((Q @ K^T)/sqrt(K)) masked, f16; causal skip; fused col sums
  gemm_bt<u16, 0, true, false, false, true><<<dim3(TT / 256, TT / 128, BB), 512, 0, stream>>>(
      QKV, QKV + 1024, SP, nullptr, Dp, KD, QKVW, QKVW, TT,
      (long long)TT * QKVW, (long long)TT * QKVW, (long long)TT * TT, INV_SQRT_K);

  // Vt = (V cols of QKV)^T scaled by 1/colsum
  transpose_v<<<dim3(VD / 32, TT / 32, BB), tb, 0, stream>>>(QKV, Dp, Vt);

  // read = P @ (Di*V), K truncated at r0+256, deepest-first
  gemm_bt<float, 0, false, true, false, false><<<dim3(TT / 256, VD / 128, BB), 512, 0, stream>>>(
      SP, Vt, out + CC, nullptr, nullptr, TT, TT, TT, OUTW,
      (long long)TT * TT, (long long)VD * TT, (long long)TT * OUTW, 1.f);
}